// Round 1
// baseline (273.987 us; speedup 1.0000x reference)
//
#include <hip/hip_runtime.h>
#include <hip/hip_bf16.h>
#include <stdint.h>

#define B_SZ 8192
#define D_SZ 512
#define U_SZ 512
#define M_SZ 16
#define K_SZ 64

#define BROWS 64   // b-rows per block
#define BU 128     // u-cols per block
#define BK 64      // k-tile for B staging

typedef short bf16x8 __attribute__((ext_vector_type(8)));
typedef float f32x4 __attribute__((ext_vector_type(4)));

__device__ __forceinline__ unsigned short f2bf(float f) {
  union { float f; unsigned u; } v; v.f = f;
  unsigned r = v.u + 0x7fffu + ((v.u >> 16) & 1u);
  return (unsigned short)(r >> 16);
}

// async global->LDS, 16B per lane; LDS dest = wave-uniform base + lane*16
__device__ __forceinline__ void async16(const void* gptr, void* ldsptr) {
  __builtin_amdgcn_global_load_lds(
      (const __attribute__((address_space(1))) unsigned int*)gptr,
      (__attribute__((address_space(3))) unsigned int*)ldsptr,
      16, 0, 0);
}

// ---------------- x f32 -> bf16 ----------------
__global__ __launch_bounds__(256) void cvt_x(const float* __restrict__ x,
                                             unsigned short* __restrict__ xb) {
  int i = (blockIdx.x * 256 + threadIdx.x) * 4;
  float4 v = *(const float4*)(x + i);
  ushort4 o;
  o.x = f2bf(v.x); o.y = f2bf(v.y); o.z = f2bf(v.z); o.w = f2bf(v.w);
  *(ushort4*)(xb + i) = o;
}

// ------- kernels [M,D,U] f32 -> kT [M,U,D] bf16 (tile transpose) -------
__global__ __launch_bounds__(256) void cvt_kT(const float* __restrict__ kin,
                                              unsigned short* __restrict__ kT) {
  __shared__ float tile[32][33];
  int m = blockIdx.z, d0 = blockIdx.y * 32, u0 = blockIdx.x * 32;
  int tx = threadIdx.x & 31, ty = threadIdx.x >> 5;  // ty in 0..7
  const float* src = kin + ((size_t)m * D_SZ + d0) * U_SZ + u0;
#pragma unroll
  for (int p = 0; p < 4; ++p)
    tile[ty + p * 8][tx] = src[(size_t)(ty + p * 8) * U_SZ + tx];
  __syncthreads();
  unsigned short* dst = kT + ((size_t)m * U_SZ + u0) * D_SZ + d0;
#pragma unroll
  for (int p = 0; p < 4; ++p)
    dst[(size_t)(ty + p * 8) * D_SZ + tx] = f2bf(tile[tx][ty + p * 8]);
}

// ---------------- sim[b,m] = 1/(||x@Wk + bk - keys_m|| + 1) ----------------
__global__ __launch_bounds__(256) void sim_kernel(
    const float* __restrict__ x, const float* __restrict__ key_kernel,
    const float* __restrict__ key_bias, const float* __restrict__ keys_map,
    float* __restrict__ sim) {
  __shared__ float xs[16 * 512];   // 32 KB
  __shared__ float kv[16 * 64];    // 4 KB
  int t = threadIdx.x;
  int b0 = blockIdx.x * 16;
  // stage 16 rows of x (fp32, coalesced float4)
  const float4* xg = (const float4*)(x + (size_t)b0 * D_SZ);
  float4* xs4 = (float4*)xs;
#pragma unroll
  for (int q = 0; q < 8; ++q) xs4[q * 256 + t] = xg[q * 256 + t];
  __syncthreads();
  int row = t >> 4, tk = t & 15;  // 16 rows x 16 k-quads
  float4 acc = *(const float4*)(key_bias + tk * 4);
  const float* xrow = xs + row * 512;
#pragma unroll 4
  for (int d = 0; d < 512; ++d) {
    float4 kk = *(const float4*)(key_kernel + (size_t)d * 64 + tk * 4);
    float xv = xrow[d];
    acc.x += xv * kk.x; acc.y += xv * kk.y;
    acc.z += xv * kk.z; acc.w += xv * kk.w;
  }
  *(float4*)(kv + row * 64 + tk * 4) = acc;
  __syncthreads();
  // thread -> (row, mode)
  int mm = t & 15;
  const float* kvr = kv + row * 64;
  const float* km = keys_map + mm * 64;
  float d2 = 0.f;
#pragma unroll 8
  for (int k = 0; k < 64; ++k) {
    float df = kvr[k] - km[k];
    d2 += df * df;
  }
  sim[(size_t)(b0 + row) * M_SZ + mm] = 1.0f / (sqrtf(d2) + 1.0f);
}

// ---------------- main weighted GEMM ----------------
// out[b,u] = (1/16) * sum_m sim[b,m] * ( x[b,:] @ kernels[m,:,u] + biases[m,u] )
__global__ __launch_bounds__(256, 2) void poly_gemm(
    const unsigned short* __restrict__ xb,  // [B][D] bf16
    const unsigned short* __restrict__ kT,  // [M][U][D] bf16
    const float* __restrict__ sim,          // [B][M]
    const float* __restrict__ biases,       // [M][U]
    float* __restrict__ out) {              // [B][U]
  __shared__ unsigned short sA[BROWS * D_SZ];  // 64x512 bf16 = 64 KB (full K resident)
  __shared__ unsigned short sB[BU * BK];       // 128x64 bf16 = 16 KB

  int t = threadIdx.x;
  int w = t >> 6, l = t & 63;
  int bid = blockIdx.x;
  // XCD swizzle: blocks round-robin over 8 XCDs; pin each u-tile to 2 XCDs so
  // its 2MB kernels slice stays L2-resident.
  int ut = (bid & 7) >> 1;                 // 0..3
  int bt = ((bid >> 3) << 1) | (bid & 1);  // 0..127
  int b0 = bt * BROWS;
  int u0 = ut * BU;

  // stage full A row-block: 64 rows x 512 k, one 1KB chunk per row
  const unsigned short* xsrc = xb + (size_t)b0 * D_SZ;
#pragma unroll
  for (int c = 0; c < 16; ++c) {
    int ch = w * 16 + c;  // chunk == row
    async16(xsrc + (size_t)ch * D_SZ + l * 8, (char*)sA + ch * 1024);
  }

  int wi = w >> 1, wj = w & 1;  // 2x2 wave grid, each wave 32x64
  int rbase = wi * 32, cbase = wj * 64;
  int lane16 = l & 15, quad = l >> 4;

  f32x4 facc[2][4];
#pragma unroll
  for (int i = 0; i < 2; ++i)
#pragma unroll
    for (int j = 0; j < 4; ++j) facc[i][j] = (f32x4){0.f, 0.f, 0.f, 0.f};

  for (int m = 0; m < M_SZ; ++m) {
    f32x4 pacc[2][4];
#pragma unroll
    for (int i = 0; i < 2; ++i)
#pragma unroll
      for (int j = 0; j < 4; ++j) pacc[i][j] = (f32x4){0.f, 0.f, 0.f, 0.f};

    const unsigned short* bsrc = kT + ((size_t)m * U_SZ + u0) * D_SZ;
    for (int kt = 0; kt < D_SZ / BK; ++kt) {
      __syncthreads();  // previous compute done before LDS overwrite
      // stage B tile: 128 u-rows x 64 k; 16 chunks of 1KB; 4 per wave
#pragma unroll
      for (int c = 0; c < 4; ++c) {
        int ch = w * 4 + c;
        int urow = ch * 8 + (l >> 3);
        int kk8 = (l & 7) * 8;
        async16(bsrc + (size_t)urow * D_SZ + kt * BK + kk8, (char*)sB + ch * 1024);
      }
      __syncthreads();  // staging visible (vmcnt drain + barrier)
#pragma unroll
      for (int h = 0; h < 2; ++h) {
        bf16x8 af[2], bfr[4];
        int kb = kt * BK + h * 32 + quad * 8;
#pragma unroll
        for (int i = 0; i < 2; ++i)
          af[i] = *(const bf16x8*)(sA + (size_t)(rbase + i * 16 + lane16) * D_SZ + kb);
        int kbb = h * 32 + quad * 8;
#pragma unroll
        for (int j = 0; j < 4; ++j)
          bfr[j] = *(const bf16x8*)(sB + (size_t)(cbase + j * 16 + lane16) * BK + kbb);
#pragma unroll
        for (int i = 0; i < 2; ++i)
#pragma unroll
          for (int j = 0; j < 4; ++j)
            pacc[i][j] = __builtin_amdgcn_mfma_f32_16x16x32_bf16(
                af[i], bfr[j], pacc[i][j], 0, 0, 0);
      }
    }
    // facc += sim[row,m] * (pacc + biases[m,u])
    float bv[4];
#pragma unroll
    for (int j = 0; j < 4; ++j)
      bv[j] = biases[(size_t)m * U_SZ + u0 + cbase + j * 16 + lane16];
#pragma unroll
    for (int i = 0; i < 2; ++i)
#pragma unroll
      for (int r = 0; r < 4; ++r) {
        int row = b0 + rbase + i * 16 + quad * 4 + r;
        float s = sim[(size_t)row * M_SZ + m];
#pragma unroll
        for (int j = 0; j < 4; ++j)
          facc[i][j][r] += s * (pacc[i][j][r] + bv[j]);
      }
  }

  // epilogue: out = facc / 16
  float* orow = out + (size_t)b0 * U_SZ + u0;
#pragma unroll
  for (int i = 0; i < 2; ++i)
#pragma unroll
    for (int r = 0; r < 4; ++r) {
      int row = rbase + i * 16 + quad * 4 + r;
#pragma unroll
      for (int j = 0; j < 4; ++j)
        orow[(size_t)row * U_SZ + cbase + j * 16 + lane16] =
            facc[i][j][r] * 0.0625f;
    }
}

extern "C" void kernel_launch(void* const* d_in, const int* in_sizes, int n_in,
                              void* d_out, int out_size, void* d_ws, size_t ws_size,
                              hipStream_t stream) {
  const float* x = (const float*)d_in[0];
  const float* key_kernel = (const float*)d_in[1];
  const float* key_bias = (const float*)d_in[2];
  const float* keys_map = (const float*)d_in[3];
  const float* kernels = (const float*)d_in[4];
  const float* biases = (const float*)d_in[5];
  float* out = (float*)d_out;

  // ws layout: xb (8 MB) | kT (8 MB) | sim (0.5 MB)  -> 16.5 MB total
  unsigned short* xb = (unsigned short*)d_ws;
  unsigned short* kT = xb + (size_t)B_SZ * D_SZ;
  float* sim = (float*)((char*)d_ws + 2 * (size_t)B_SZ * D_SZ +
                        2 * (size_t)M_SZ * U_SZ * D_SZ);

  cvt_x<<<dim3((B_SZ * D_SZ) / 1024), 256, 0, stream>>>(x, xb);
  cvt_kT<<<dim3(U_SZ / 32, D_SZ / 32, M_SZ), 256, 0, stream>>>(kernels, kT);
  sim_kernel<<<dim3(B_SZ / 16), 256, 0, stream>>>(x, key_kernel, key_bias,
                                                  keys_map, sim);
  poly_gemm<<<dim3(512), 256, 0, stream>>>(xb, kT, sim, biases, out);
}

// Round 2
// 197.342 us; speedup vs baseline: 1.3884x; 1.3884x over previous
//
#include <hip/hip_runtime.h>
#include <hip/hip_bf16.h>
#include <stdint.h>

#define B_SZ 8192
#define D_SZ 512
#define U_SZ 512
#define M_SZ 16
#define K_SZ 64

#define BROWS 64   // b-rows per block
#define BU 128     // u-cols per block
#define BK 64      // k-tile for B staging

typedef short bf16x8 __attribute__((ext_vector_type(8)));
typedef float f32x4 __attribute__((ext_vector_type(4)));

__device__ __forceinline__ unsigned short f2bf(float f) {
  union { float f; unsigned u; } v; v.f = f;
  unsigned r = v.u + 0x7fffu + ((v.u >> 16) & 1u);
  return (unsigned short)(r >> 16);
}

// async global->LDS, 16B per lane; LDS dest = wave-uniform base + lane*16
__device__ __forceinline__ void async16(const void* gptr, void* ldsptr) {
  __builtin_amdgcn_global_load_lds(
      (const __attribute__((address_space(1))) unsigned int*)gptr,
      (__attribute__((address_space(3))) unsigned int*)ldsptr,
      16, 0, 0);
}

// ------- kernels [M,D,U] f32 -> kT [M,U,D] bf16 (tile transpose, vectorized) -------
// tile: 32 d x 64 u, float4 reads, 16B stores.
__global__ __launch_bounds__(256) void cvt_kT(const float* __restrict__ kin,
                                              unsigned short* __restrict__ kT) {
  __shared__ float tf[32][65];  // +1 pad breaks bank alignment
  int m = blockIdx.z, d0 = blockIdx.y * 32, u0 = blockIdx.x * 64;
  int t = threadIdx.x;
  {
    int dr = t >> 4, uc = t & 15;  // 16 d-rows x 16 u-quads per pass
    const float* src = kin + ((size_t)(m * D_SZ + d0 + dr)) * U_SZ + u0 + uc * 4;
    float4 a = *(const float4*)src;
    float4 b = *(const float4*)(src + 16 * U_SZ);
    tf[dr][uc * 4 + 0] = a.x; tf[dr][uc * 4 + 1] = a.y;
    tf[dr][uc * 4 + 2] = a.z; tf[dr][uc * 4 + 3] = a.w;
    tf[dr + 16][uc * 4 + 0] = b.x; tf[dr + 16][uc * 4 + 1] = b.y;
    tf[dr + 16][uc * 4 + 2] = b.z; tf[dr + 16][uc * 4 + 3] = b.w;
  }
  __syncthreads();
  {
    int ur = t >> 2, dc = t & 3;  // 64 u-rows x 4 d-octs
    unsigned short* dst = kT + ((size_t)(m * U_SZ + u0 + ur)) * D_SZ + d0 + dc * 8;
    ushort4 lo, hi;
    lo.x = f2bf(tf[dc * 8 + 0][ur]); lo.y = f2bf(tf[dc * 8 + 1][ur]);
    lo.z = f2bf(tf[dc * 8 + 2][ur]); lo.w = f2bf(tf[dc * 8 + 3][ur]);
    hi.x = f2bf(tf[dc * 8 + 4][ur]); hi.y = f2bf(tf[dc * 8 + 5][ur]);
    hi.z = f2bf(tf[dc * 8 + 6][ur]); hi.w = f2bf(tf[dc * 8 + 7][ur]);
    *(ushort4*)dst = lo;
    *(ushort4*)(dst + 4) = hi;
  }
}

// ------- sim[b,m] = 1/(||x@Wk + bk - keys_m|| + 1), fused x->bf16 -------
__global__ __launch_bounds__(256) void sim_kernel(
    const float* __restrict__ x, const float* __restrict__ key_kernel,
    const float* __restrict__ key_bias, const float* __restrict__ keys_map,
    float* __restrict__ sim, unsigned short* __restrict__ xb) {
  __shared__ float xs[16 * 512];  // 32 KB
  __shared__ float ks[64 * 64];   // 16 KB (key_kernel d-chunk)
  __shared__ float kv[16 * 64];   // 4 KB
  int t = threadIdx.x;
  int b0 = blockIdx.x * 16;
  // stage 16 rows of x; fused bf16 convert-out (replaces cvt_x kernel)
  const float4* xg = (const float4*)(x + (size_t)b0 * D_SZ);
  float4* xs4 = (float4*)xs;
  ushort4* xb4 = (ushort4*)(xb + (size_t)b0 * D_SZ);
#pragma unroll
  for (int q = 0; q < 8; ++q) {
    float4 v = xg[q * 256 + t];
    xs4[q * 256 + t] = v;
    ushort4 o;
    o.x = f2bf(v.x); o.y = f2bf(v.y); o.z = f2bf(v.z); o.w = f2bf(v.w);
    xb4[q * 256 + t] = o;
  }
  int row = t >> 4, tk = t & 15;  // 16 rows x 16 k-quads
  float4 acc = *(const float4*)(key_bias + tk * 4);
  float4* ks4 = (float4*)ks;
  const float4* wk4 = (const float4*)key_kernel;
  for (int c = 0; c < 8; ++c) {
    __syncthreads();  // also covers initial x staging on c==0
#pragma unroll
    for (int q = 0; q < 4; ++q) ks4[q * 256 + t] = wk4[c * 1024 + q * 256 + t];
    __syncthreads();
    const float* xrow = xs + row * 512 + c * 64;
#pragma unroll 8
    for (int dd = 0; dd < 64; ++dd) {
      float4 kk = ks4[dd * 16 + tk];
      float xv = xrow[dd];
      acc.x += xv * kk.x; acc.y += xv * kk.y;
      acc.z += xv * kk.z; acc.w += xv * kk.w;
    }
  }
  *(float4*)(kv + row * 64 + tk * 4) = acc;
  __syncthreads();
  int mm = t & 15;
  const float* kvr = kv + row * 64;
  const float* km = keys_map + mm * 64;
  float d2 = 0.f;
#pragma unroll 8
  for (int k = 0; k < 64; ++k) {
    float df = kvr[k] - km[k];
    d2 += df * df;
  }
  sim[(size_t)(b0 + row) * M_SZ + mm] = 1.0f / (sqrtf(d2) + 1.0f);
}

// ---------------- main weighted GEMM ----------------
// out[b,u] = (1/16) * sum_m sim[b,m] * ( x[b,:] @ kernels[m,:,u] + biases[m,u] )
// LDS XOR swizzle: row r's 16B chunk c lives at physical chunk c^(r&7) so that
// MFMA fragment reads (16 rows @ same k) spread over all 32 banks (2-way = free).
__global__ __launch_bounds__(256, 2) void poly_gemm(
    const unsigned short* __restrict__ xb,  // [B][D] bf16
    const unsigned short* __restrict__ kT,  // [M][U][D] bf16
    const float* __restrict__ sim,          // [B][M]
    const float* __restrict__ biases,       // [M][U]
    float* __restrict__ out) {              // [B][U]
  __shared__ unsigned short sA[BROWS * D_SZ];  // 64x512 bf16 = 64 KB (full K resident)
  __shared__ unsigned short sB[BU * BK];       // 128x64 bf16 = 16 KB

  int t = threadIdx.x;
  int w = t >> 6, l = t & 63;
  int bid = blockIdx.x;
  int ut = (bid & 7) >> 1;                 // 0..3 (pin u-tile to XCD pair)
  int bt = ((bid >> 3) << 1) | (bid & 1);  // 0..127
  int b0 = bt * BROWS;
  int u0 = ut * BU;

  // stage full A row-block with swizzle: LDS phys chunk p of row r holds
  // global chunk p^(r&7)  (source-permuted since LDS dest is fixed lane*16)
  const unsigned short* xsrc = xb + (size_t)b0 * D_SZ;
#pragma unroll
  for (int c = 0; c < 16; ++c) {
    int ch = w * 16 + c;  // chunk == row
    async16(xsrc + (size_t)ch * D_SZ + (size_t)(l ^ (ch & 7)) * 8,
            (char*)sA + ch * 1024);
  }

  int wi = w >> 1, wj = w & 1;  // 2x2 wave grid, each wave 32x64
  int rbase = wi * 32, cbase = wj * 64;
  int lane16 = l & 15, quad = l >> 4;
  int sw = lane16 & 7;  // row&7 for all fragment rows this lane touches

  f32x4 facc[2][4];
#pragma unroll
  for (int i = 0; i < 2; ++i)
#pragma unroll
    for (int j = 0; j < 4; ++j) facc[i][j] = (f32x4){0.f, 0.f, 0.f, 0.f};

  for (int m = 0; m < M_SZ; ++m) {
    f32x4 pacc[2][4];
#pragma unroll
    for (int i = 0; i < 2; ++i)
#pragma unroll
      for (int j = 0; j < 4; ++j) pacc[i][j] = (f32x4){0.f, 0.f, 0.f, 0.f};

    const unsigned short* bsrc = kT + ((size_t)m * U_SZ + u0) * D_SZ;
    for (int kt = 0; kt < D_SZ / BK; ++kt) {
      __syncthreads();  // previous compute done before LDS overwrite
      // stage B tile 128u x 64k with swizzle; urow&7 == l>>3 within a chunk
#pragma unroll
      for (int c = 0; c < 4; ++c) {
        int ch = w * 4 + c;
        int urow = ch * 8 + (l >> 3);
        int kk8 = ((l & 7) ^ (l >> 3)) * 8;
        async16(bsrc + (size_t)urow * D_SZ + kt * BK + kk8, (char*)sB + ch * 1024);
      }
      __syncthreads();  // staging visible
#pragma unroll
      for (int h = 0; h < 2; ++h) {
        bf16x8 af[2], bfr[4];
        int ckA = kt * 8 + h * 4 + quad;   // logical 16B chunk in A row
        int pA = ckA ^ sw;                 // low-3 swizzle
#pragma unroll
        for (int i = 0; i < 2; ++i)
          af[i] = *(const bf16x8*)(sA + (size_t)(rbase + i * 16 + lane16) * D_SZ + pA * 8);
        int ckB = h * 4 + quad;            // 0..7
        int pB = ckB ^ sw;
#pragma unroll
        for (int j = 0; j < 4; ++j)
          bfr[j] = *(const bf16x8*)(sB + (size_t)(cbase + j * 16 + lane16) * BK + pB * 8);
#pragma unroll
        for (int i = 0; i < 2; ++i)
#pragma unroll
          for (int j = 0; j < 4; ++j)
            pacc[i][j] = __builtin_amdgcn_mfma_f32_16x16x32_bf16(
                af[i], bfr[j], pacc[i][j], 0, 0, 0);
      }
    }
    // facc += sim[row,m] * (pacc + biases[m,u])
    float bv[4];
#pragma unroll
    for (int j = 0; j < 4; ++j)
      bv[j] = biases[(size_t)m * U_SZ + u0 + cbase + j * 16 + lane16];
#pragma unroll
    for (int i = 0; i < 2; ++i)
#pragma unroll
      for (int r = 0; r < 4; ++r) {
        int row = b0 + rbase + i * 16 + quad * 4 + r;
        float s = sim[(size_t)row * M_SZ + m];
#pragma unroll
        for (int j = 0; j < 4; ++j)
          facc[i][j][r] += s * (pacc[i][j][r] + bv[j]);
      }
  }

  // epilogue: out = facc / 16
  float* orow = out + (size_t)b0 * U_SZ + u0;
#pragma unroll
  for (int i = 0; i < 2; ++i)
#pragma unroll
    for (int r = 0; r < 4; ++r) {
      int row = rbase + i * 16 + quad * 4 + r;
#pragma unroll
      for (int j = 0; j < 4; ++j)
        orow[(size_t)row * U_SZ + cbase + j * 16 + lane16] =
            facc[i][j][r] * 0.0625f;
    }
}

extern "C" void kernel_launch(void* const* d_in, const int* in_sizes, int n_in,
                              void* d_out, int out_size, void* d_ws, size_t ws_size,
                              hipStream_t stream) {
  const float* x = (const float*)d_in[0];
  const float* key_kernel = (const float*)d_in[1];
  const float* key_bias = (const float*)d_in[2];
  const float* keys_map = (const float*)d_in[3];
  const float* kernels = (const float*)d_in[4];
  const float* biases = (const float*)d_in[5];
  float* out = (float*)d_out;

  // ws layout: xb (8 MB) | kT (8 MB) | sim (0.5 MB)
  unsigned short* xb = (unsigned short*)d_ws;
  unsigned short* kT = xb + (size_t)B_SZ * D_SZ;
  float* sim = (float*)((char*)d_ws + 2 * (size_t)B_SZ * D_SZ +
                        2 * (size_t)M_SZ * U_SZ * D_SZ);

  cvt_kT<<<dim3(U_SZ / 64, D_SZ / 32, M_SZ), 256, 0, stream>>>(kernels, kT);
  sim_kernel<<<dim3(B_SZ / 16), 256, 0, stream>>>(x, key_kernel, key_bias,
                                                  keys_map, sim, xb);
  poly_gemm<<<dim3(512), 256, 0, stream>>>(xb, kT, sim, biases, out);
}